// Round 15
// baseline (905.825 us; speedup 1.0000x reference)
//
#include <hip/hip_runtime.h>
#include <hip/hip_bf16.h>

#define DIM 128
#define NN 40000
#define NE 640000
#define NBLK ((NN + 255) / 256)   // 157
#define PGRID 1536                 // persistent grid: 75% of 2048-block capacity

// gfx950 bf16 MFMA fragment types (learn_hip m89/m93/m97):
typedef __attribute__((ext_vector_type(8))) short s16x8;   // 8 bf16 in 4 VGPRs
typedef __attribute__((ext_vector_type(4))) float f32x4;
typedef __attribute__((ext_vector_type(4))) unsigned short u16x4;
typedef __attribute__((ext_vector_type(4))) unsigned int u32x4;

__device__ __forceinline__ float bf16_lo(unsigned v) { return __uint_as_float(v << 16); }
__device__ __forceinline__ float bf16_hi(unsigned v) { return __uint_as_float(v & 0xffff0000u); }
__device__ __forceinline__ unsigned short f_to_bf16(float f) {
    unsigned u = __float_as_uint(f);
    u += 0x7fffu + ((u >> 16) & 1u);   // round-to-nearest-even
    return (unsigned short)(u >> 16);
}

__global__ void fill_const_f32(float* __restrict__ out, int n, float v) {
    int i = blockIdx.x * blockDim.x + threadIdx.x;
    if (i < n) out[i] = v;
}

// ---------------- software grid barrier (device-scope, cross-XCD safe) ----------
// bar[0] = arrive count, bar[1] = generation. Zeroed by hipMemsetAsync each call.
// Safe: launch_bounds(256,8) caps VGPR at 64 -> 2048-block capacity; grid is
// 1536, so all blocks are co-resident regardless of placement.
__device__ __forceinline__ void gsync(int* bar) {
    __syncthreads();
    if (threadIdx.x == 0) {
        __threadfence();   // agent-scope release of this block's prior writes
        int g = __hip_atomic_load(&bar[1], __ATOMIC_RELAXED, __HIP_MEMORY_SCOPE_AGENT);
        int a = __hip_atomic_fetch_add(&bar[0], 1, __ATOMIC_ACQ_REL, __HIP_MEMORY_SCOPE_AGENT);
        if (a == (int)gridDim.x - 1) {
            __hip_atomic_store(&bar[0], 0, __ATOMIC_RELAXED, __HIP_MEMORY_SCOPE_AGENT);
            __hip_atomic_fetch_add(&bar[1], 1, __ATOMIC_RELEASE, __HIP_MEMORY_SCOPE_AGENT);
        } else {
            while (__hip_atomic_load(&bar[1], __ATOMIC_ACQUIRE, __HIP_MEMORY_SCOPE_AGENT) == g)
                __builtin_amdgcn_s_sleep(2);
        }
        __threadfence();   // agent-scope acquire before consuming others' writes
    }
    __syncthreads();
}

// ---------------- persistent prep: cvt + CSR build, 4 grid barriers ----------
__global__ __launch_bounds__(256, 8) void prep(
    const float* __restrict__ x, const int* __restrict__ ei,
    const float* __restrict__ W1l, const float* __restrict__ W1r,
    const float* __restrict__ W2l, const float* __restrict__ W2r,
    unsigned short* __restrict__ xb, unsigned short* __restrict__ Wb,
    int* __restrict__ deg, int* __restrict__ bsum, int* __restrict__ row_ptr,
    int* __restrict__ cursor, int* __restrict__ fmtflag,
    int* __restrict__ sorted, int* __restrict__ bar) {
    __shared__ int sh[256];
    int tid = threadIdx.x, bid = blockIdx.x;
    int gidx = bid * 256 + tid;
    const int GSZ = PGRID * 256;   // 393,216

    // ---- P0: zero deg + detect edge_index dtype ----
    for (int i = gidx; i < NN; i += GSZ) deg[i] = 0;
    if (bid == 0 && tid < 64) {
        // int64 passthrough: odd words (high halves, values < 40000) all zero
        int w = ei[2 * tid + 1];
        unsigned long long m = __ballot(w == 0);
        if (tid == 0)
            __hip_atomic_store(fmtflag, (m == ~0ull) ? 1 : 0,
                               __ATOMIC_RELAXED, __HIP_MEMORY_SCOPE_AGENT);
    }
    gsync(bar);

    int fmt = __hip_atomic_load(fmtflag, __ATOMIC_RELAXED, __HIP_MEMORY_SCOPE_AGENT);

    // ---- P1: count degrees ----
    for (int e = gidx; e < NE; e += GSZ) {
        int dst = fmt ? ((const int2*)ei)[NE + e].x : ei[NE + e];
        if ((unsigned)dst < (unsigned)NN) atomicAdd(&deg[dst], 1);
    }
    gsync(bar);

    // ---- P2: per-chunk block sums ----
    if (bid < NBLK) {
        int i = bid * 256 + tid;
        sh[tid] = (i < NN) ? deg[i] : 0;
        __syncthreads();
        for (int off = 128; off > 0; off >>= 1) {
            if (tid < off) sh[tid] += sh[tid + off];
            __syncthreads();
        }
        if (tid == 0) bsum[bid] = sh[0];
    }
    gsync(bar);

    // ---- P3: each chunk-block: LDS-scan the 157 sums (no serial tail) + local scan ----
    if (bid < NBLK) {
        int v0 = (tid < NBLK) ? bsum[tid] : 0;
        sh[tid] = v0;
        __syncthreads();
        for (int off = 1; off < 256; off <<= 1) {
            int u = (tid >= off) ? sh[tid - off] : 0;
            __syncthreads();
            sh[tid] += u;
            __syncthreads();
        }
        int base = sh[bid] - bsum[bid];   // exclusive prefix of earlier chunks
        __syncthreads();
        int i = bid * 256 + tid;
        int v = (i < NN) ? deg[i] : 0;
        sh[tid] = v;
        __syncthreads();
        for (int off = 1; off < 256; off <<= 1) {
            int u = (tid >= off) ? sh[tid - off] : 0;
            __syncthreads();
            sh[tid] += u;
            __syncthreads();
        }
        int excl = sh[tid] - v + base;
        if (i < NN) { row_ptr[i] = excl; cursor[i] = excl; }
        if (i == NN - 1) row_ptr[NN] = excl + v;
    }
    gsync(bar);

    // ---- P4: fill CSR + cvt x + cvt weights (independent, same phase) ----
    for (int e = gidx; e < NE; e += GSZ) {
        int src, dst;
        if (fmt) {
            src = ((const int2*)ei)[e].x;
            dst = ((const int2*)ei)[NE + e].x;
        } else {
            src = ei[e];
            dst = ei[NE + e];
        }
        if ((unsigned)dst < (unsigned)NN) {
            int pos = atomicAdd(&cursor[dst], 1);
            if ((unsigned)pos < (unsigned)NE) sorted[pos] = src;
        }
    }
    for (int g = gidx; g < 1280000; g += GSZ) {
        f32x4 v = *(const f32x4*)(x + 4 * (size_t)g);
        u16x4 o;
        o.x = f_to_bf16(v.x); o.y = f_to_bf16(v.y);
        o.z = f_to_bf16(v.z); o.w = f_to_bf16(v.w);
        *(u16x4*)(xb + 4 * (size_t)g) = o;
    }
    if (gidx < 16384) {
        int m = gidx >> 12;               // matrix 0..3, 4096 groups each
        const float* src = (m == 0) ? W1l : (m == 1) ? W1r : (m == 2) ? W2l : W2r;
        size_t off = (size_t)(gidx & 4095) * 4;
        f32x4 v = *(const f32x4*)(src + off);
        u16x4 o;
        o.x = f_to_bf16(v.x); o.y = f_to_bf16(v.y);
        o.z = f_to_bf16(v.z); o.w = f_to_bf16(v.w);
        *(u16x4*)(Wb + (size_t)m * 16384 + off) = o;
    }
}

// ---------------- mean aggregation: one 16-lane group per node (r11-proven) ----
__global__ __launch_bounds__(256) void aggregate_g(
    const unsigned short* __restrict__ xin,
    const int* __restrict__ row_ptr,
    const int* __restrict__ sorted_src,
    unsigned short* __restrict__ mean_out) {
    int lane = threadIdx.x & 63;
    int wv = threadIdx.x >> 6;
    int grp = lane >> 4;     // node within wave
    int lid = lane & 15;     // 16 B sub-chunk of the 256 B row
    int n = blockIdx.x * 16 + wv * 4 + grp;
    int start = row_ptr[n], end = row_ptr[n + 1];

    float a[8] = {0.f, 0.f, 0.f, 0.f, 0.f, 0.f, 0.f, 0.f};
    int i = start;
    for (; i + 3 < end; i += 4) {
        int s0 = sorted_src[i];
        int s1 = sorted_src[i + 1];
        int s2 = sorted_src[i + 2];
        int s3 = sorted_src[i + 3];
        u32x4 v0 = *(const u32x4*)(xin + (size_t)s0 * DIM + lid * 8);
        u32x4 v1 = *(const u32x4*)(xin + (size_t)s1 * DIM + lid * 8);
        u32x4 v2 = *(const u32x4*)(xin + (size_t)s2 * DIM + lid * 8);
        u32x4 v3 = *(const u32x4*)(xin + (size_t)s3 * DIM + lid * 8);
        a[0] += bf16_lo(v0.x) + bf16_lo(v1.x) + bf16_lo(v2.x) + bf16_lo(v3.x);
        a[1] += bf16_hi(v0.x) + bf16_hi(v1.x) + bf16_hi(v2.x) + bf16_hi(v3.x);
        a[2] += bf16_lo(v0.y) + bf16_lo(v1.y) + bf16_lo(v2.y) + bf16_lo(v3.y);
        a[3] += bf16_hi(v0.y) + bf16_hi(v1.y) + bf16_hi(v2.y) + bf16_hi(v3.y);
        a[4] += bf16_lo(v0.z) + bf16_lo(v1.z) + bf16_lo(v2.z) + bf16_lo(v3.z);
        a[5] += bf16_hi(v0.z) + bf16_hi(v1.z) + bf16_hi(v2.z) + bf16_hi(v3.z);
        a[6] += bf16_lo(v0.w) + bf16_lo(v1.w) + bf16_lo(v2.w) + bf16_lo(v3.w);
        a[7] += bf16_hi(v0.w) + bf16_hi(v1.w) + bf16_hi(v2.w) + bf16_hi(v3.w);
    }
    for (; i < end; ++i) {
        int s = sorted_src[i];
        u32x4 v = *(const u32x4*)(xin + (size_t)s * DIM + lid * 8);
        a[0] += bf16_lo(v.x); a[1] += bf16_hi(v.x);
        a[2] += bf16_lo(v.y); a[3] += bf16_hi(v.y);
        a[4] += bf16_lo(v.z); a[5] += bf16_hi(v.z);
        a[6] += bf16_lo(v.w); a[7] += bf16_hi(v.w);
    }

    int d = end - start;
    float inv = 1.f / (float)(d > 1 ? d : 1);
    u32x4 o;
    o.x = (unsigned)f_to_bf16(a[0] * inv) | ((unsigned)f_to_bf16(a[1] * inv) << 16);
    o.y = (unsigned)f_to_bf16(a[2] * inv) | ((unsigned)f_to_bf16(a[3] * inv) << 16);
    o.z = (unsigned)f_to_bf16(a[4] * inv) | ((unsigned)f_to_bf16(a[5] * inv) << 16);
    o.w = (unsigned)f_to_bf16(a[6] * inv) | ((unsigned)f_to_bf16(a[7] * inv) << 16);
    *(u32x4*)(mean_out + (size_t)n * DIM + lid * 8) = o;
}

// ---------------- fused SAGE linear: relu(mean@Wl^T + b + h@Wr^T) (r11-proven) ----
// 64 rows x 16 cols per wave: 4 stacked 16x16 tiles, B-frags loaded once and
// reused 4x, A double-buffered. mfma_f32_16x16x32_bf16 layouts (m89/m120):
//   A: A[m=lane&15][k=quad*8+j]; B = W[col][k..k+7]; C/D: col=lane&15, row=quad*4+reg.
template <bool WRITE_F32>
__global__ __launch_bounds__(256) void sage_gemm(
    const unsigned short* __restrict__ mean,
    const unsigned short* __restrict__ hself,
    const unsigned short* __restrict__ Wl,
    const unsigned short* __restrict__ Wr,
    const float* __restrict__ bias,
    void* __restrict__ outv) {
    int lane = threadIdx.x & 63;
    int wv = threadIdx.x >> 6;
    int quad = lane >> 4;
    int lid = lane & 15;
    int row0 = blockIdx.x * 64;
    int bcol = blockIdx.y * 64 + wv * 16 + lid;

    const unsigned short* wl0 = Wl + (size_t)bcol * DIM + quad * 8;
    const unsigned short* wr0 = Wr + (size_t)bcol * DIM + quad * 8;
    s16x8 bl[4], br[4];
#pragma unroll
    for (int kb = 0; kb < 4; ++kb) {
        bl[kb] = *(const s16x8*)(wl0 + kb * 32);
        br[kb] = *(const s16x8*)(wr0 + kb * 32);
    }

    const unsigned short* ap = mean + (size_t)(row0 + lid) * DIM + quad * 8;
    const unsigned short* hp = hself + (size_t)(row0 + lid) * DIM + quad * 8;
    const int TS = 16 * DIM;

    f32x4 acc[4] = {{0,0,0,0},{0,0,0,0},{0,0,0,0},{0,0,0,0}};
    s16x8 am[2][4], ah[2][4];

#pragma unroll
    for (int kb = 0; kb < 4; ++kb) {
        am[0][kb] = *(const s16x8*)(ap + kb * 32);
        ah[0][kb] = *(const s16x8*)(hp + kb * 32);
    }
#pragma unroll
    for (int t = 0; t < 4; ++t) {
        int cb = t & 1, nb = (t + 1) & 1;
        if (t < 3) {
#pragma unroll
            for (int kb = 0; kb < 4; ++kb) {
                am[nb][kb] = *(const s16x8*)(ap + (t + 1) * TS + kb * 32);
                ah[nb][kb] = *(const s16x8*)(hp + (t + 1) * TS + kb * 32);
            }
        }
#pragma unroll
        for (int kb = 0; kb < 4; ++kb)
            acc[t] = __builtin_amdgcn_mfma_f32_16x16x32_bf16(am[cb][kb], bl[kb], acc[t], 0, 0, 0);
#pragma unroll
        for (int kb = 0; kb < 4; ++kb)
            acc[t] = __builtin_amdgcn_mfma_f32_16x16x32_bf16(ah[cb][kb], br[kb], acc[t], 0, 0, 0);
    }

    float bv = bias[bcol];
#pragma unroll
    for (int t = 0; t < 4; ++t) {
#pragma unroll
        for (int r = 0; r < 4; ++r) {
            int orow = row0 + t * 16 + quad * 4 + r;
            float v = fmaxf(acc[t][r] + bv, 0.f);   // relu
            if (WRITE_F32)
                ((float*)outv)[(size_t)orow * DIM + bcol] = v;
            else
                ((unsigned short*)outv)[(size_t)orow * DIM + bcol] = f_to_bf16(v);
        }
    }
}

// ---------------- launch ----------------

extern "C" void kernel_launch(void* const* d_in, const int* in_sizes, int n_in,
                              void* d_out, int out_size, void* d_ws, size_t ws_size,
                              hipStream_t stream) {
    const float* x   = (const float*)d_in[0];
    const int*   ei  = (const int*)d_in[1];
    const float* W1l = (const float*)d_in[2];
    const float* b1l = (const float*)d_in[3];
    const float* W1r = (const float*)d_in[4];
    const float* W2l = (const float*)d_in[5];
    const float* b2l = (const float*)d_in[6];
    const float* W2r = (const float*)d_in[7];
    float* out = (float*)d_out;

    const int OUT_ELEMS = NN * DIM;        // 5,120,000

    // workspace layout (256B-aligned)
    const size_t OFF_DEG  = 0;             // N ints
    const size_t OFF_ROW  = 163840;        // N+1 ints
    const size_t OFF_BSUM = 324608;        // NBLK ints (in ROW region slack)
    const size_t OFF_CUR  = 327680;        // N ints
    const size_t OFF_FMT  = 491264;        // 1 int
    const size_t OFF_BAR  = 491328;        // 2 ints (barrier state)
    const size_t OFF_SRT  = 491520;        // E ints
    const size_t OFF_WB   = 3051520;       // 4 * 16384 bf16
    const size_t OFF_XB   = 3182592;       // N*128 bf16
    const size_t OFF_MEAN = 13422592;      // N*128 bf16
    const size_t OFF_H1   = 23662592;      // N*128 bf16
    const size_t NEEDED   = 33902592;

    if (ws_size < NEEDED) {
        fill_const_f32<<<(OUT_ELEMS + 255) / 256, 256, 0, stream>>>(out, OUT_ELEMS, 50.0f);
        return;
    }

    char* ws = (char*)d_ws;
    int* deg     = (int*)(ws + OFF_DEG);
    int* row_ptr = (int*)(ws + OFF_ROW);
    int* bsum    = (int*)(ws + OFF_BSUM);
    int* cursor  = (int*)(ws + OFF_CUR);
    int* fmtflag = (int*)(ws + OFF_FMT);
    int* bar     = (int*)(ws + OFF_BAR);
    int* sorted  = (int*)(ws + OFF_SRT);
    unsigned short* Wb    = (unsigned short*)(ws + OFF_WB);
    unsigned short* xb    = (unsigned short*)(ws + OFF_XB);
    unsigned short* meanb = (unsigned short*)(ws + OFF_MEAN);
    unsigned short* h1b   = (unsigned short*)(ws + OFF_H1);
    unsigned short* W1lb = Wb;
    unsigned short* W1rb = Wb + 16384;
    unsigned short* W2lb = Wb + 32768;
    unsigned short* W2rb = Wb + 49152;

    // 1: zero barrier state (ws is re-poisoned 0xAA before every call)
    hipMemsetAsync(bar, 0, 2 * sizeof(int), stream);
    // 2: persistent prep — cvt + CSR build with internal grid barriers
    prep<<<PGRID, 256, 0, stream>>>(x, ei, W1l, W1r, W2l, W2r, xb, Wb,
                                    deg, bsum, row_ptr, cursor, fmtflag, sorted, bar);

    // 3-4: layer 1
    aggregate_g<<<NN / 16, 256, 0, stream>>>(xb, row_ptr, sorted, meanb);
    sage_gemm<false><<<dim3(NN / 64, 2), 256, 0, stream>>>(meanb, xb, W1lb, W1rb, b1l, h1b);

    // 5-6: layer 2
    aggregate_g<<<NN / 16, 256, 0, stream>>>(h1b, row_ptr, sorted, meanb);
    sage_gemm<true><<<dim3(NN / 64, 2), 256, 0, stream>>>(meanb, h1b, W2lb, W2rb, b2l, out);
}

// Round 16
// 243.289 us; speedup vs baseline: 3.7232x; 3.7232x over previous
//
#include <hip/hip_runtime.h>
#include <hip/hip_bf16.h>

#define DIM 128
#define NN 40000
#define NE 640000
#define NBLK ((NN + 255) / 256)   // 157

// gfx950 bf16 MFMA fragment types (learn_hip m89/m93/m97):
typedef __attribute__((ext_vector_type(8))) short s16x8;   // 8 bf16 in 4 VGPRs
typedef __attribute__((ext_vector_type(4))) float f32x4;
typedef __attribute__((ext_vector_type(4))) unsigned short u16x4;
typedef __attribute__((ext_vector_type(4))) unsigned int u32x4;

__device__ __forceinline__ float bf16_lo(unsigned v) { return __uint_as_float(v << 16); }
__device__ __forceinline__ float bf16_hi(unsigned v) { return __uint_as_float(v & 0xffff0000u); }
__device__ __forceinline__ unsigned short f_to_bf16(float f) {
    unsigned u = __float_as_uint(f);
    u += 0x7fffu + ((u >> 16) & 1u);   // round-to-nearest-even
    return (unsigned short)(u >> 16);
}

__global__ void fill_const_f32(float* __restrict__ out, int n, float v) {
    int i = blockIdx.x * blockDim.x + threadIdx.x;
    if (i < n) out[i] = v;
}

// ---------------- fused: fp32->bf16 cvt (x + weights) + zero deg + fmt detect ----
// blocks 0..4999: x (4 elems/thread); 5000..5063: weights; 5064..5220: zero deg
// (+ block 5064 lanes 0..63 detect int64-vs-int32 edge_index).
__global__ void cvt_all(const float* __restrict__ x, unsigned short* __restrict__ xb,
                        const float* __restrict__ w0, const float* __restrict__ w1,
                        const float* __restrict__ w2, const float* __restrict__ w3,
                        unsigned short* __restrict__ wb,
                        int* __restrict__ deg, const int* __restrict__ ei,
                        int* __restrict__ flag) {
    int b = blockIdx.x;
    if (b >= 5064) {
        int i = (b - 5064) * 256 + threadIdx.x;
        if (i < NN) deg[i] = 0;
        if (b == 5064 && threadIdx.x < 64) {
            // int64 passthrough: odd words (high halves, values < 40000) all zero
            int w = ei[2 * threadIdx.x + 1];
            unsigned long long m = __ballot(w == 0);
            if (threadIdx.x == 0) *flag = (m == ~0ull) ? 1 : 0;   // 1 = int64
        }
        return;
    }
    const float* src;
    unsigned short* dst;
    size_t i;
    if (b < 5000) {
        src = x; dst = xb;
        i = (size_t)b * 256 + threadIdx.x;           // 1,280,000 f32x4 groups
    } else {
        int w = b - 5000;
        int m = w >> 4;                               // matrix 0..3
        src = (m == 0) ? w0 : (m == 1) ? w1 : (m == 2) ? w2 : w3;
        dst = wb + (size_t)m * 16384;
        i = (size_t)(w & 15) * 256 + threadIdx.x;     // 4096 groups per matrix
    }
    f32x4 v = *(const f32x4*)(src + 4 * i);
    u16x4 o;
    o.x = f_to_bf16(v.x); o.y = f_to_bf16(v.y);
    o.z = f_to_bf16(v.z); o.w = f_to_bf16(v.w);
    *(u16x4*)(dst + 4 * i) = o;
}

// ---------------- CSR build ----------------

__global__ void count_deg(const int* __restrict__ ei, const int* __restrict__ fmt,
                          int* __restrict__ deg) {
    int e = blockIdx.x * blockDim.x + threadIdx.x;
    if (e >= NE) return;
    int dst = (*fmt) ? ((const int2*)ei)[NE + e].x : ei[NE + e];
    if ((unsigned)dst < (unsigned)NN) atomicAdd(&deg[dst], 1);
}

__global__ void block_sums(const int* __restrict__ deg, int* __restrict__ bsum) {
    __shared__ int sh[256];
    int i = blockIdx.x * 256 + threadIdx.x;
    sh[threadIdx.x] = (i < NN) ? deg[i] : 0;
    __syncthreads();
    for (int off = 128; off > 0; off >>= 1) {
        if (threadIdx.x < off) sh[threadIdx.x] += sh[threadIdx.x + off];
        __syncthreads();
    }
    if (threadIdx.x == 0) bsum[blockIdx.x] = sh[0];
}

// merged scan: each block redundantly LDS-scans the 157 block sums (8 steps,
// no serial tail) to get its base, then local-scans its 256 deg entries.
__global__ void scan_block2(const int* __restrict__ deg, const int* __restrict__ bsum,
                            int* __restrict__ row_ptr, int* __restrict__ cursor) {
    __shared__ int sh[256];
    int t = threadIdx.x, bid = blockIdx.x;

    int v0 = (t < NBLK) ? bsum[t] : 0;
    sh[t] = v0;
    __syncthreads();
    for (int off = 1; off < 256; off <<= 1) {
        int u = (t >= off) ? sh[t - off] : 0;
        __syncthreads();
        sh[t] += u;
        __syncthreads();
    }
    int base = sh[bid] - bsum[bid];   // exclusive prefix of earlier chunks
    __syncthreads();

    int i = bid * 256 + t;
    int v = (i < NN) ? deg[i] : 0;
    sh[t] = v;
    __syncthreads();
    for (int off = 1; off < 256; off <<= 1) {
        int u = (t >= off) ? sh[t - off] : 0;
        __syncthreads();
        sh[t] += u;
        __syncthreads();
    }
    int excl = sh[t] - v + base;
    if (i < NN) { row_ptr[i] = excl; cursor[i] = excl; }
    if (i == NN - 1) row_ptr[NN] = excl + v;
}

__global__ void fill_csr(const int* __restrict__ ei, const int* __restrict__ fmt,
                         int* __restrict__ cursor, int* __restrict__ sorted_src) {
    int e = blockIdx.x * blockDim.x + threadIdx.x;
    if (e >= NE) return;
    int src, dst;
    if (*fmt) {
        src = ((const int2*)ei)[e].x;
        dst = ((const int2*)ei)[NE + e].x;
    } else {
        src = ei[e];
        dst = ei[NE + e];
    }
    if ((unsigned)dst >= (unsigned)NN) return;
    int pos = atomicAdd(&cursor[dst], 1);
    if ((unsigned)pos < (unsigned)NE) sorted_src[pos] = src;
}

// ---------------- mean aggregation: one 16-lane group per node (r11-proven) ----
// 4 nodes per wave in parallel; each lane owns 16 B of its node's row;
// accumulators ARE the output fragment — zero shuffles, zero LDS. x4 unroll.

__global__ __launch_bounds__(256) void aggregate_g(
    const unsigned short* __restrict__ xin,
    const int* __restrict__ row_ptr,
    const int* __restrict__ sorted_src,
    unsigned short* __restrict__ mean_out) {
    int lane = threadIdx.x & 63;
    int wv = threadIdx.x >> 6;
    int grp = lane >> 4;     // node within wave
    int lid = lane & 15;     // 16 B sub-chunk of the 256 B row
    int n = blockIdx.x * 16 + wv * 4 + grp;
    int start = row_ptr[n], end = row_ptr[n + 1];

    float a[8] = {0.f, 0.f, 0.f, 0.f, 0.f, 0.f, 0.f, 0.f};
    int i = start;
    for (; i + 3 < end; i += 4) {
        int s0 = sorted_src[i];
        int s1 = sorted_src[i + 1];
        int s2 = sorted_src[i + 2];
        int s3 = sorted_src[i + 3];
        u32x4 v0 = *(const u32x4*)(xin + (size_t)s0 * DIM + lid * 8);
        u32x4 v1 = *(const u32x4*)(xin + (size_t)s1 * DIM + lid * 8);
        u32x4 v2 = *(const u32x4*)(xin + (size_t)s2 * DIM + lid * 8);
        u32x4 v3 = *(const u32x4*)(xin + (size_t)s3 * DIM + lid * 8);
        a[0] += bf16_lo(v0.x) + bf16_lo(v1.x) + bf16_lo(v2.x) + bf16_lo(v3.x);
        a[1] += bf16_hi(v0.x) + bf16_hi(v1.x) + bf16_hi(v2.x) + bf16_hi(v3.x);
        a[2] += bf16_lo(v0.y) + bf16_lo(v1.y) + bf16_lo(v2.y) + bf16_lo(v3.y);
        a[3] += bf16_hi(v0.y) + bf16_hi(v1.y) + bf16_hi(v2.y) + bf16_hi(v3.y);
        a[4] += bf16_lo(v0.z) + bf16_lo(v1.z) + bf16_lo(v2.z) + bf16_lo(v3.z);
        a[5] += bf16_hi(v0.z) + bf16_hi(v1.z) + bf16_hi(v2.z) + bf16_hi(v3.z);
        a[6] += bf16_lo(v0.w) + bf16_lo(v1.w) + bf16_lo(v2.w) + bf16_lo(v3.w);
        a[7] += bf16_hi(v0.w) + bf16_hi(v1.w) + bf16_hi(v2.w) + bf16_hi(v3.w);
    }
    for (; i < end; ++i) {
        int s = sorted_src[i];
        u32x4 v = *(const u32x4*)(xin + (size_t)s * DIM + lid * 8);
        a[0] += bf16_lo(v.x); a[1] += bf16_hi(v.x);
        a[2] += bf16_lo(v.y); a[3] += bf16_hi(v.y);
        a[4] += bf16_lo(v.z); a[5] += bf16_hi(v.z);
        a[6] += bf16_lo(v.w); a[7] += bf16_hi(v.w);
    }

    int d = end - start;
    float inv = 1.f / (float)(d > 1 ? d : 1);
    u32x4 o;
    o.x = (unsigned)f_to_bf16(a[0] * inv) | ((unsigned)f_to_bf16(a[1] * inv) << 16);
    o.y = (unsigned)f_to_bf16(a[2] * inv) | ((unsigned)f_to_bf16(a[3] * inv) << 16);
    o.z = (unsigned)f_to_bf16(a[4] * inv) | ((unsigned)f_to_bf16(a[5] * inv) << 16);
    o.w = (unsigned)f_to_bf16(a[6] * inv) | ((unsigned)f_to_bf16(a[7] * inv) << 16);
    *(u32x4*)(mean_out + (size_t)n * DIM + lid * 8) = o;
}

// ---------------- fused SAGE linear: relu(mean@Wl^T + b + h@Wr^T) (r11-proven) ----
// 64 rows x 16 cols per wave: 4 stacked 16x16 tiles, B-frags loaded once and
// reused 4x, A double-buffered. mfma_f32_16x16x32_bf16 layouts (m89/m120):
//   A: A[m=lane&15][k=quad*8+j]; B = W[col][k..k+7]; C/D: col=lane&15, row=quad*4+reg.

template <bool WRITE_F32>
__global__ __launch_bounds__(256) void sage_gemm(
    const unsigned short* __restrict__ mean,   // [N,128] bf16
    const unsigned short* __restrict__ hself,  // [N,128] bf16
    const unsigned short* __restrict__ Wl,     // [128,128] bf16
    const unsigned short* __restrict__ Wr,
    const float* __restrict__ bias,            // [128] fp32
    void* __restrict__ outv) {
    int lane = threadIdx.x & 63;
    int wv = threadIdx.x >> 6;
    int quad = lane >> 4;
    int lid = lane & 15;
    int row0 = blockIdx.x * 64;
    int bcol = blockIdx.y * 64 + wv * 16 + lid;

    const unsigned short* wl0 = Wl + (size_t)bcol * DIM + quad * 8;
    const unsigned short* wr0 = Wr + (size_t)bcol * DIM + quad * 8;
    s16x8 bl[4], br[4];
#pragma unroll
    for (int kb = 0; kb < 4; ++kb) {
        bl[kb] = *(const s16x8*)(wl0 + kb * 32);
        br[kb] = *(const s16x8*)(wr0 + kb * 32);
    }

    const unsigned short* ap = mean + (size_t)(row0 + lid) * DIM + quad * 8;
    const unsigned short* hp = hself + (size_t)(row0 + lid) * DIM + quad * 8;
    const int TS = 16 * DIM;

    f32x4 acc[4] = {{0,0,0,0},{0,0,0,0},{0,0,0,0},{0,0,0,0}};
    s16x8 am[2][4], ah[2][4];

#pragma unroll
    for (int kb = 0; kb < 4; ++kb) {
        am[0][kb] = *(const s16x8*)(ap + kb * 32);
        ah[0][kb] = *(const s16x8*)(hp + kb * 32);
    }
#pragma unroll
    for (int t = 0; t < 4; ++t) {
        int cb = t & 1, nb = (t + 1) & 1;
        if (t < 3) {
#pragma unroll
            for (int kb = 0; kb < 4; ++kb) {
                am[nb][kb] = *(const s16x8*)(ap + (t + 1) * TS + kb * 32);
                ah[nb][kb] = *(const s16x8*)(hp + (t + 1) * TS + kb * 32);
            }
        }
#pragma unroll
        for (int kb = 0; kb < 4; ++kb)
            acc[t] = __builtin_amdgcn_mfma_f32_16x16x32_bf16(am[cb][kb], bl[kb], acc[t], 0, 0, 0);
#pragma unroll
        for (int kb = 0; kb < 4; ++kb)
            acc[t] = __builtin_amdgcn_mfma_f32_16x16x32_bf16(ah[cb][kb], br[kb], acc[t], 0, 0, 0);
    }

    float bv = bias[bcol];
#pragma unroll
    for (int t = 0; t < 4; ++t) {
#pragma unroll
        for (int r = 0; r < 4; ++r) {
            int orow = row0 + t * 16 + quad * 4 + r;
            float v = fmaxf(acc[t][r] + bv, 0.f);   // relu
            if (WRITE_F32)
                ((float*)outv)[(size_t)orow * DIM + bcol] = v;
            else
                ((unsigned short*)outv)[(size_t)orow * DIM + bcol] = f_to_bf16(v);
        }
    }
}

// ---------------- launch ----------------

extern "C" void kernel_launch(void* const* d_in, const int* in_sizes, int n_in,
                              void* d_out, int out_size, void* d_ws, size_t ws_size,
                              hipStream_t stream) {
    const float* x   = (const float*)d_in[0];
    const int*   ei  = (const int*)d_in[1];
    const float* W1l = (const float*)d_in[2];
    const float* b1l = (const float*)d_in[3];
    const float* W1r = (const float*)d_in[4];
    const float* W2l = (const float*)d_in[5];
    const float* b2l = (const float*)d_in[6];
    const float* W2r = (const float*)d_in[7];
    float* out = (float*)d_out;

    const int OUT_ELEMS = NN * DIM;        // 5,120,000

    // workspace layout (256B-aligned)
    const size_t OFF_DEG  = 0;             // N ints
    const size_t OFF_ROW  = 163840;        // N+1 ints
    const size_t OFF_BSUM = 324608;        // NBLK ints (in ROW region slack)
    const size_t OFF_CUR  = 327680;        // N ints
    const size_t OFF_FMT  = 491264;        // 1 int
    const size_t OFF_SRT  = 491520;        // E ints
    const size_t OFF_WB   = 3051520;       // 4 * 16384 bf16
    const size_t OFF_XB   = 3182592;       // N*128 bf16
    const size_t OFF_MEAN = 13422592;      // N*128 bf16
    const size_t OFF_H1   = 23662592;      // N*128 bf16
    const size_t NEEDED   = 33902592;

    if (ws_size < NEEDED) {
        fill_const_f32<<<(OUT_ELEMS + 255) / 256, 256, 0, stream>>>(out, OUT_ELEMS, 50.0f);
        return;
    }

    char* ws = (char*)d_ws;
    int* deg     = (int*)(ws + OFF_DEG);
    int* row_ptr = (int*)(ws + OFF_ROW);
    int* bsum    = (int*)(ws + OFF_BSUM);
    int* cursor  = (int*)(ws + OFF_CUR);
    int* fmtflag = (int*)(ws + OFF_FMT);
    int* sorted  = (int*)(ws + OFF_SRT);
    unsigned short* Wb    = (unsigned short*)(ws + OFF_WB);
    unsigned short* xb    = (unsigned short*)(ws + OFF_XB);
    unsigned short* meanb = (unsigned short*)(ws + OFF_MEAN);
    unsigned short* h1b   = (unsigned short*)(ws + OFF_H1);
    unsigned short* W1lb = Wb;
    unsigned short* W1rb = Wb + 16384;
    unsigned short* W2lb = Wb + 32768;
    unsigned short* W2rb = Wb + 49152;

    // 1: conversions + zero deg + fmt detect
    cvt_all<<<5221, 256, 0, stream>>>(x, xb, W1l, W1r, W2l, W2r, Wb, deg, ei, fmtflag);
    // 2-5: CSR build
    count_deg<<<(NE + 255) / 256, 256, 0, stream>>>(ei, fmtflag, deg);
    block_sums<<<NBLK, 256, 0, stream>>>(deg, bsum);
    scan_block2<<<NBLK, 256, 0, stream>>>(deg, bsum, row_ptr, cursor);
    fill_csr<<<(NE + 255) / 256, 256, 0, stream>>>(ei, fmtflag, cursor, sorted);

    // 6-7: layer 1
    aggregate_g<<<NN / 16, 256, 0, stream>>>(xb, row_ptr, sorted, meanb);
    sage_gemm<false><<<dim3(NN / 64, 2), 256, 0, stream>>>(meanb, xb, W1lb, W1rb, b1l, h1b);

    // 8-9: layer 2
    aggregate_g<<<NN / 16, 256, 0, stream>>>(h1b, row_ptr, sorted, meanb);
    sage_gemm<true><<<dim3(NN / 64, 2), 256, 0, stream>>>(meanb, h1b, W2lb, W2rb, b2l, out);
}